// Round 1
// baseline (4056.167 us; speedup 1.0000x reference)
//
#include <hip/hip_runtime.h>
#include <math.h>

#define Bv 8
#define Nv 2048
#define DIMv 1024
#define Hv 16
#define Dv 64
#define Rv 5
#define RMv 10

// output layout (flat concat, fp32)
#define ATTN_OFF 0
#define ESC_OFF (Bv * Nv * DIMv)            // 16777216
#define RSC_OFF (ESC_OFF + Bv * Hv * Nv * Rv) // 18087936
#define KL_OFF  (RSC_OFF + Bv * Hv * Nv * Rv) // 19398656

#define BM 64
#define BK 16
#define AS_STRIDE (BM + 4)    // 68  -> row stride * 4B = 272 B (16B aligned)
#define BS_STRIDE (128 + 4)   // 132 -> 528 B (16B aligned)
#define CT_STRIDE (128 + 4)

// grid: (N/BM, H, B); block: 256 threads
__global__ __launch_bounds__(256, 4)
void svgp_main(const float* __restrict__ x, const float* __restrict__ mask,
               const float* __restrict__ eps, const float* __restrict__ qk_w,
               const float* __restrict__ we_p, const float* __restrict__ wr_p,
               const float* __restrict__ log_lam, const float* __restrict__ m_u,
               const float* __restrict__ s_tri, const float* __restrict__ log_ssqrt,
               const float* __restrict__ fw_w, const float* __restrict__ fw_b,
               float* __restrict__ out)
{
    const int nt = blockIdx.x, h = blockIdx.y, b = blockIdx.z;
    const int n0 = nt * BM;
    const int t = threadIdx.x;

    // big LDS region: aliased between GEMM staging (sA+sB) and C-tile
    __shared__ float smem[BM * CT_STRIDE];                 // 8448 floats = 33792 B
    float (*sA)[AS_STRIDE] = (float (*)[AS_STRIDE])smem;           // 16x68
    float (*sB)[BS_STRIDE] = (float (*)[BS_STRIDE])(smem + BK * AS_STRIDE); // 16x132
    float (*sCt)[CT_STRIDE] = (float (*)[CT_STRIDE])smem;          // 64x132

    __shared__ float sS[Rv][Rv][Rv];  // S[a][u][c] for this head
    __shared__ float sMu[Rv][Rv];     // m_u[h][a][s]
    __shared__ float sFw[Dv][Rv];     // fw_w[d][r]
    __shared__ float sFb[Dv];
    __shared__ float sLam2[Rv];

    // ---- small-table init (no sync needed until epilogue; GEMM syncs cover it)
    if (t < 125) {
        int a = t / 25, u = (t % 25) / 5, c = t % 5;
        float v = 0.f;
        if (u == c)      v = expf(log_ssqrt[(h * Rv + a) * Rv + u]);
        else if (u > c)  v = s_tri[((h * Rv + a) * Rv + u) * Rv + c];
        sS[a][u][c] = v;
    }
    if (t >= 128 && t < 153) { int i = t - 128; sMu[i / 5][i % 5] = m_u[(h * Rv) * Rv + i]; }
    if (t >= 160 && t < 165) sLam2[t - 160] = expf(2.f * log_lam[h * Rv + (t - 160)]);
    if (t >= 192 && t < 256) sFb[t - 192] = fw_b[t - 192];
    if (t < 320) { /* always true for t<256; cover all 320 via two slots */ }
    // fw_w: 320 floats, 256 threads -> two strided passes
    if (t < 320) sFw[t / Rv][t % Rv] = fw_w[t];
    {
        int t2 = t + 256;
        if (t2 < 320) sFw[t2 / Rv][t2 % Rv] = fw_w[t2];
    }

    // ---- GEMM: C[64 x 128] = x_tile[64 x 1024] * W^T, W rows = q(h) ++ k(h)
    const float* xb = x + ((size_t)b * Nv + n0) * DIMv;
    const int tr = t & 15;   // row group (4 rows)
    const int tc = t >> 4;   // col group (8 cols)

    float acc[4][8];
#pragma unroll
    for (int i = 0; i < 4; ++i)
#pragma unroll
        for (int j = 0; j < 8; ++j) acc[i][j] = 0.f;

    for (int k0 = 0; k0 < DIMv; k0 += BK) {
        // stage A: 64 rows x 16 k, transposed into sA[k][row]
        {
            int row = t >> 2;
            int kq = (t & 3) * 4;
            const float4 v = *(const float4*)(xb + (size_t)row * DIMv + k0 + kq);
            sA[kq + 0][row] = v.x; sA[kq + 1][row] = v.y;
            sA[kq + 2][row] = v.z; sA[kq + 3][row] = v.w;
        }
        // stage B: 128 rows x 16 k, transposed into sB[k][j]
#pragma unroll
        for (int l = 0; l < 2; ++l) {
            int lin = l * 256 + t;
            int jj = lin >> 2;
            int kq = (lin & 3) * 4;
            int jg = (jj < 64) ? (h * Dv + jj) : (DIMv + h * Dv + (jj - 64));
            const float4 v = *(const float4*)(qk_w + (size_t)jg * DIMv + k0 + kq);
            sB[kq + 0][jj] = v.x; sB[kq + 1][jj] = v.y;
            sB[kq + 2][jj] = v.z; sB[kq + 3][jj] = v.w;
        }
        __syncthreads();
#pragma unroll
        for (int kk = 0; kk < BK; ++kk) {
            float4 a4 = *(const float4*)&sA[kk][tr * 4];
            float4 b0 = *(const float4*)&sB[kk][tc * 8];
            float4 b1 = *(const float4*)&sB[kk][tc * 8 + 4];
            float av[4] = {a4.x, a4.y, a4.z, a4.w};
            float bv[8] = {b0.x, b0.y, b0.z, b0.w, b1.x, b1.y, b1.z, b1.w};
#pragma unroll
            for (int i = 0; i < 4; ++i)
#pragma unroll
                for (int j = 0; j < 8; ++j)
                    acc[i][j] = fmaf(av[i], bv[j], acc[i][j]);
        }
        __syncthreads();
    }

    // ---- spill C tile to LDS (aliases sA/sB; last loop iter ended with sync)
#pragma unroll
    for (int i = 0; i < 4; ++i) {
        int row = tr * 4 + i;
#pragma unroll
        for (int j = 0; j < 8; ++j) sCt[row][tc * 8 + j] = acc[i][j];
    }
    __syncthreads();

    // ---- epilogue: wave per row; lane = d
    const int lane = t & 63;
    const int sub = t >> 6;

    // we/wr for this (b,h,d): recompute from x directly (rm=10 sampled columns)
    float weR[Rv], wrR[Rv];
    {
        float xv[RMv];
#pragma unroll
        for (int m = 0; m < RMv; ++m) {
            int nidx = (m == RMv - 1) ? (Nv - 1) : (int)((float)m * (2047.0f / 9.0f));
            xv[m] = x[((size_t)b * Nv + nidx) * DIMv + h * Dv + lane];
        }
#pragma unroll
        for (int rr = 0; rr < Rv; ++rr) {
            float sw = 0.f, sr = 0.f;
#pragma unroll
            for (int m = 0; m < RMv; ++m) {
                sw = fmaf(xv[m], we_p[(h * RMv + m) * Rv + rr], sw);
                sr = fmaf(xv[m], wr_p[(h * RMv + m) * Rv + rr], sr);
            }
            weR[rr] = sw; wrR[rr] = sr;
        }
    }

    for (int it = 0; it < BM / 4; ++it) {
        const int row = it * 4 + sub;
        const int n = n0 + row;
        const float mk = mask[b * Nv + n];
        const float qv = sCt[row][lane] * mk;
        const float kv = sCt[row][64 + lane] * mk;

        // 12 fused butterfly reductions: |q|^2, |k|^2, 5 q.we, 5 k.wr
        float red[12];
        red[0] = qv * qv;
        red[1] = kv * kv;
#pragma unroll
        for (int rr = 0; rr < Rv; ++rr) {
            red[2 + rr] = qv * weR[rr];
            red[7 + rr] = kv * wrR[rr];
        }
#pragma unroll
        for (int off = 32; off > 0; off >>= 1) {
#pragma unroll
            for (int j = 0; j < 12; ++j)
                red[j] += __shfl_xor(red[j], off, 64);
        }
        const float qn = fmaxf(sqrtf(red[0]), 1e-12f);
        const float kn = fmaxf(sqrtf(red[1]), 1e-12f);

        float esc[Rv], rsc[Rv], v1[Rv];
#pragma unroll
        for (int rr = 0; rr < Rv; ++rr) {
            esc[rr] = red[2 + rr] / qn;
            rsc[rr] = red[7 + rr] / kn;
            v1[rr] = (esc[rr] + rsc[rr]) * sLam2[rr];
        }

        const size_t ebase = (((size_t)b * Hv + h) * Nv + n) * Rv;
        float ev[Rv];
#pragma unroll
        for (int u = 0; u < Rv; ++u) ev[u] = eps[ebase + u];

        // samples[c] = mean[c] + noise[c]
        float smp[Rv];
#pragma unroll
        for (int c = 0; c < Rv; ++c) {
            float mn = 0.f;
#pragma unroll
            for (int a = 0; a < Rv; ++a) mn = fmaf(v1[a], sMu[a][c], mn);
            float nz = 0.f;
#pragma unroll
            for (int u = 0; u < Rv; ++u) {
                float s = 0.f;
#pragma unroll
                for (int a = 0; a < Rv; ++a) s = fmaf(v1[a], sS[a][u][c], s);
                nz = fmaf(s, ev[u], nz);
            }
            smp[c] = mn + nz;
        }

        // attn_out[d] = samples . fw_w[d,:] + fw_b[d]
        float ao = sFb[lane];
#pragma unroll
        for (int rr = 0; rr < Rv; ++rr) ao = fmaf(smp[rr], sFw[lane][rr], ao);
        out[ATTN_OFF + ((size_t)b * Nv + n) * DIMv + h * Dv + lane] = ao;

        // escore / rscore (uniform across wave after butterfly)
#pragma unroll
        for (int rr = 0; rr < Rv; ++rr) {
            if (lane == rr)      out[ESC_OFF + ebase + rr] = esc[rr];
            if (lane == 8 + rr)  out[RSC_OFF + ebase + rr] = rsc[rr];
        }
    }
}

__global__ void svgp_kl(const float* __restrict__ log_lam, const float* __restrict__ m_u,
                        const float* __restrict__ s_tri, const float* __restrict__ log_ssqrt,
                        float* __restrict__ out)
{
    __shared__ float red[256];
    const int t = threadIdx.x;
    float acc = 0.f;

    // term1: 0.5 * sum (lam2[h,a] * S[h,a,u,c])^2 over 16*5*5*5
    for (int idx = t; idx < Hv * Rv * Rv * Rv; idx += 256) {
        int hh = idx / 125;
        int rem = idx % 125;
        int a = rem / 25, u = (rem / 5) % 5, c = rem % 5;
        float S = 0.f;
        if (u == c)      S = expf(log_ssqrt[(hh * Rv + a) * Rv + u]);
        else if (u > c)  S = s_tri[((hh * Rv + a) * Rv + u) * Rv + c];
        float lam2 = expf(2.f * log_lam[hh * Rv + a]);
        float z = lam2 * S;
        acc += 0.5f * z * z;
    }
    // term2 + term3: 400 entries each
    for (int idx = t; idx < Hv * Rv * Rv; idx += 256) {
        int hh = idx / 25, a = (idx / 5) % 5;
        float e4 = expf(4.f * log_lam[hh * Rv + a]);
        float mu = m_u[idx];
        acc += 0.5f * e4 * mu * mu;
        acc -= log_ssqrt[idx];
    }
    // term4: -2*r*sum(log_lam)
    for (int idx = t; idx < Hv * Rv; idx += 256) acc -= 2.f * (float)Rv * log_lam[idx];

    red[t] = acc;
    __syncthreads();
    for (int s = 128; s > 0; s >>= 1) {
        if (t < s) red[t] += red[t + s];
        __syncthreads();
    }
    if (t == 0) out[KL_OFF] = red[0] - 0.5f * (float)(Rv * Rv * Hv);
}

extern "C" void kernel_launch(void* const* d_in, const int* in_sizes, int n_in,
                              void* d_out, int out_size, void* d_ws, size_t ws_size,
                              hipStream_t stream) {
    const float* x        = (const float*)d_in[0];
    const float* mask     = (const float*)d_in[1];
    const float* eps      = (const float*)d_in[2];
    const float* qk_w     = (const float*)d_in[3];
    const float* we_p     = (const float*)d_in[4];
    const float* wr_p     = (const float*)d_in[5];
    const float* log_lam  = (const float*)d_in[6];
    const float* m_u      = (const float*)d_in[7];
    const float* s_tri    = (const float*)d_in[8];
    const float* log_ssqrt= (const float*)d_in[9];
    const float* fw_w     = (const float*)d_in[10];
    const float* fw_b     = (const float*)d_in[11];
    float* out = (float*)d_out;

    dim3 grid(Nv / BM, Hv, Bv);
    svgp_main<<<grid, 256, 0, stream>>>(x, mask, eps, qk_w, we_p, wr_p, log_lam,
                                        m_u, s_tri, log_ssqrt, fw_w, fw_b, out);
    svgp_kl<<<1, 256, 0, stream>>>(log_lam, m_u, s_tri, log_ssqrt, out);
}

// Round 2
// 3580.375 us; speedup vs baseline: 1.1329x; 1.1329x over previous
//
#include <hip/hip_runtime.h>
#include <math.h>

#define Bv 8
#define Nv 2048
#define DIMv 1024
#define Hv 16
#define Dv 64
#define Rv 5
#define RMv 10

// output layout (flat concat, fp32)
#define ATTN_OFF 0
#define ESC_OFF (Bv * Nv * DIMv)              // 16777216
#define RSC_OFF (ESC_OFF + Bv * Hv * Nv * Rv) // 18087936
#define KL_OFF  (RSC_OFF + Bv * Hv * Nv * Rv) // 19398656

#define BM 64       // n-rows per block
#define BKC 32      // k-chunk (one mfma_16x16x32 per chunk per tile-pair)
#define CT_STRIDE (128 + 4)

using half8 = __attribute__((ext_vector_type(8))) _Float16;
using f32x4 = __attribute__((ext_vector_type(4))) float;

// grid: 4096 1-D (XCD-swizzled); block: 256 threads = 4 waves
__global__ __launch_bounds__(256, 4)
void svgp_main(const float* __restrict__ x, const float* __restrict__ mask,
               const float* __restrict__ eps, const float* __restrict__ qk_w,
               const float* __restrict__ we_p, const float* __restrict__ wr_p,
               const float* __restrict__ log_lam, const float* __restrict__ m_u,
               const float* __restrict__ s_tri, const float* __restrict__ log_ssqrt,
               const float* __restrict__ fw_w, const float* __restrict__ fw_b,
               float* __restrict__ out)
{
    // XCD-affinity decode: xcd = id%8 owns heads {2*xcd, 2*xcd+1} -> qk_w slice
    // (1 MB fp32) stays L2-resident per XCD; x streamed once per XCD.
    const int id = blockIdx.x;
    const int xcd = id & 7;
    const int slot = id >> 3;
    const int h = 2 * xcd + (slot & 1);
    const int idx = slot >> 1;
    const int nt = idx & 31;
    const int b = idx >> 5;
    const int n0 = nt * BM;
    const int t = threadIdx.x;
    const int lane = t & 63;
    const int wv = t >> 6;          // wave id 0..3

    // LDS: staging (A 4KB fp16 + B 8KB fp16) aliased with C-tile (33.8KB fp32)
    __shared__ float smem[BM * CT_STRIDE];          // 8448 floats = 33792 B
    _Float16* sAh = (_Float16*)smem;                // 2048 fp16: 4 mtiles x 64 lanes x 8
    _Float16* sBh = sAh + 2048;                     // 4096 fp16: 8 ntiles x 64 lanes x 8
    float (*sCt)[CT_STRIDE] = (float (*)[CT_STRIDE])smem;

    __shared__ float sS[Rv][Rv][Rv];
    __shared__ float sMu[Rv][Rv];
    __shared__ float sFw[Dv][Rv];
    __shared__ float sFb[Dv];
    __shared__ float sLam2[Rv];

    // ---- small tables (ordered before epilogue by the GEMM's barriers)
    if (t < 125) {
        int a = t / 25, u = (t % 25) / 5, c = t % 5;
        float v = 0.f;
        if (u == c)      v = expf(log_ssqrt[(h * Rv + a) * Rv + u]);
        else if (u > c)  v = s_tri[((h * Rv + a) * Rv + u) * Rv + c];
        sS[a][u][c] = v;
    }
    if (t >= 128 && t < 153) { int i = t - 128; sMu[i / 5][i % 5] = m_u[h * Rv * Rv + i]; }
    if (t >= 160 && t < 165) sLam2[t - 160] = expf(2.f * log_lam[h * Rv + (t - 160)]);
    if (t >= 192 && t < 256) sFb[t - 192] = fw_b[t - 192];
    if (t < 320) sFw[t / Rv][t % Rv] = fw_w[t];
    { int t2 = t + 256; if (t2 < 320) sFw[t2 / Rv][t2 % Rv] = fw_w[t2]; }

    // ---- MFMA GEMM: C[64 x 128] = x_tile[64 x 1024] * W^T (W rows: q(h) ++ k(h))
    // wave wv: m-half = wv>>1 (32 rows), n-half = wv&1 (64 cols)
    const float* xb = x + ((size_t)b * Nv + n0) * DIMv;
    const int mh = wv >> 1, nh = wv & 1;

    f32x4 acc[2][4];
#pragma unroll
    for (int i = 0; i < 2; ++i)
#pragma unroll
        for (int j = 0; j < 4; ++j) acc[i][j] = (f32x4){0.f, 0.f, 0.f, 0.f};

    // staging assignment: A: thread t -> row t>>2, quad t&3 (8 consecutive k)
    const int arow = t >> 2, aq = t & 3;

    for (int k0 = 0; k0 < DIMv; k0 += BKC) {
        // A tile: 64 rows x 32 k, fp32->fp16, fragment-major LDS
        {
            const float* src = xb + (size_t)arow * DIMv + k0 + aq * 8;
            float4 v0 = *(const float4*)src;
            float4 v1 = *(const float4*)(src + 4);
            half8 hv = {(_Float16)v0.x, (_Float16)v0.y, (_Float16)v0.z, (_Float16)v0.w,
                        (_Float16)v1.x, (_Float16)v1.y, (_Float16)v1.z, (_Float16)v1.w};
            int slotA = ((arow >> 4) << 6) + (arow & 15) + (aq << 4);
            *(half8*)(sAh + slotA * 8) = hv;
        }
        // B tile: 128 rows (q64|k64 of head h) x 32 k
#pragma unroll
        for (int l = 0; l < 2; ++l) {
            int lin = l * 256 + t;
            int jj = lin >> 2, bq = lin & 3;
            int jg = (jj < 64) ? (h * Dv + jj) : (DIMv + h * Dv + (jj - 64));
            const float* src = qk_w + (size_t)jg * DIMv + k0 + bq * 8;
            float4 v0 = *(const float4*)src;
            float4 v1 = *(const float4*)(src + 4);
            half8 hv = {(_Float16)v0.x, (_Float16)v0.y, (_Float16)v0.z, (_Float16)v0.w,
                        (_Float16)v1.x, (_Float16)v1.y, (_Float16)v1.z, (_Float16)v1.w};
            int slotB = ((jj >> 4) << 6) + (jj & 15) + (bq << 4);
            *(half8*)(sBh + slotB * 8) = hv;
        }
        __syncthreads();

        half8 af[2], bf[4];
#pragma unroll
        for (int i = 0; i < 2; ++i)
            af[i] = *(half8*)(sAh + ((mh * 2 + i) * 64 + lane) * 8);
#pragma unroll
        for (int j = 0; j < 4; ++j)
            bf[j] = *(half8*)(sBh + ((nh * 4 + j) * 64 + lane) * 8);
#pragma unroll
        for (int i = 0; i < 2; ++i)
#pragma unroll
            for (int j = 0; j < 4; ++j)
                acc[i][j] = __builtin_amdgcn_mfma_f32_16x16x32_f16(af[i], bf[j], acc[i][j], 0, 0, 0);
        __syncthreads();
    }

    // ---- spill C to LDS (C/D layout: col=lane&15, row=(lane>>4)*4+reg)
#pragma unroll
    for (int i = 0; i < 2; ++i) {
        int rbase = mh * 32 + i * 16 + (lane >> 4) * 4;
        int col = nh * 64 + (lane & 15);
#pragma unroll
        for (int j = 0; j < 4; ++j) {
#pragma unroll
            for (int reg = 0; reg < 4; ++reg)
                sCt[rbase + reg][col + j * 16] = acc[i][j][reg];
        }
    }
    __syncthreads();

    // ---- epilogue: wave per row; lane = d  (verified in round 1)
    const int sub = wv;

    float weR[Rv], wrR[Rv];
    {
        float xv[RMv];
#pragma unroll
        for (int m = 0; m < RMv; ++m) {
            int nidx = (m == RMv - 1) ? (Nv - 1) : (int)((float)m * (2047.0f / 9.0f));
            xv[m] = x[((size_t)b * Nv + nidx) * DIMv + h * Dv + lane];
        }
#pragma unroll
        for (int rr = 0; rr < Rv; ++rr) {
            float sw = 0.f, sr = 0.f;
#pragma unroll
            for (int m = 0; m < RMv; ++m) {
                sw = fmaf(xv[m], we_p[(h * RMv + m) * Rv + rr], sw);
                sr = fmaf(xv[m], wr_p[(h * RMv + m) * Rv + rr], sr);
            }
            weR[rr] = sw; wrR[rr] = sr;
        }
    }

    for (int it = 0; it < BM / 4; ++it) {
        const int row = it * 4 + sub;
        const int n = n0 + row;
        const float mk = mask[b * Nv + n];
        const float qv = sCt[row][lane] * mk;
        const float kv = sCt[row][64 + lane] * mk;

        float red[12];
        red[0] = qv * qv;
        red[1] = kv * kv;
#pragma unroll
        for (int rr = 0; rr < Rv; ++rr) {
            red[2 + rr] = qv * weR[rr];
            red[7 + rr] = kv * wrR[rr];
        }
#pragma unroll
        for (int off = 32; off > 0; off >>= 1) {
#pragma unroll
            for (int j = 0; j < 12; ++j)
                red[j] += __shfl_xor(red[j], off, 64);
        }
        const float qn = fmaxf(sqrtf(red[0]), 1e-12f);
        const float kn = fmaxf(sqrtf(red[1]), 1e-12f);

        float esc[Rv], rsc[Rv], v1[Rv];
#pragma unroll
        for (int rr = 0; rr < Rv; ++rr) {
            esc[rr] = red[2 + rr] / qn;
            rsc[rr] = red[7 + rr] / kn;
            v1[rr] = (esc[rr] + rsc[rr]) * sLam2[rr];
        }

        const size_t ebase = (((size_t)b * Hv + h) * Nv + n) * Rv;
        float ev[Rv];
#pragma unroll
        for (int u = 0; u < Rv; ++u) ev[u] = eps[ebase + u];

        float smp[Rv];
#pragma unroll
        for (int c = 0; c < Rv; ++c) {
            float mn = 0.f;
#pragma unroll
            for (int a = 0; a < Rv; ++a) mn = fmaf(v1[a], sMu[a][c], mn);
            float nz = 0.f;
#pragma unroll
            for (int u = 0; u < Rv; ++u) {
                float s = 0.f;
#pragma unroll
                for (int a = 0; a < Rv; ++a) s = fmaf(v1[a], sS[a][u][c], s);
                nz = fmaf(s, ev[u], nz);
            }
            smp[c] = mn + nz;
        }

        float ao = sFb[lane];
#pragma unroll
        for (int rr = 0; rr < Rv; ++rr) ao = fmaf(smp[rr], sFw[lane][rr], ao);
        out[ATTN_OFF + ((size_t)b * Nv + n) * DIMv + h * Dv + lane] = ao;

#pragma unroll
        for (int rr = 0; rr < Rv; ++rr) {
            if (lane == rr)      out[ESC_OFF + ebase + rr] = esc[rr];
            if (lane == 8 + rr)  out[RSC_OFF + ebase + rr] = rsc[rr];
        }
    }
}

__global__ void svgp_kl(const float* __restrict__ log_lam, const float* __restrict__ m_u,
                        const float* __restrict__ s_tri, const float* __restrict__ log_ssqrt,
                        float* __restrict__ out)
{
    __shared__ float red[256];
    const int t = threadIdx.x;
    float acc = 0.f;

    for (int idx = t; idx < Hv * Rv * Rv * Rv; idx += 256) {
        int hh = idx / 125;
        int rem = idx % 125;
        int a = rem / 25, u = (rem / 5) % 5, c = rem % 5;
        float S = 0.f;
        if (u == c)      S = expf(log_ssqrt[(hh * Rv + a) * Rv + u]);
        else if (u > c)  S = s_tri[((hh * Rv + a) * Rv + u) * Rv + c];
        float lam2 = expf(2.f * log_lam[hh * Rv + a]);
        float z = lam2 * S;
        acc += 0.5f * z * z;
    }
    for (int idx = t; idx < Hv * Rv * Rv; idx += 256) {
        int hh = idx / 25, a = (idx / 5) % 5;
        float e4 = expf(4.f * log_lam[hh * Rv + a]);
        float mu = m_u[idx];
        acc += 0.5f * e4 * mu * mu;
        acc -= log_ssqrt[idx];
    }
    for (int idx = t; idx < Hv * Rv; idx += 256) acc -= 2.f * (float)Rv * log_lam[idx];

    red[t] = acc;
    __syncthreads();
    for (int s = 128; s > 0; s >>= 1) {
        if (t < s) red[t] += red[t + s];
        __syncthreads();
    }
    if (t == 0) out[KL_OFF] = red[0] - 0.5f * (float)(Rv * Rv * Hv);
}

extern "C" void kernel_launch(void* const* d_in, const int* in_sizes, int n_in,
                              void* d_out, int out_size, void* d_ws, size_t ws_size,
                              hipStream_t stream) {
    const float* x        = (const float*)d_in[0];
    const float* mask     = (const float*)d_in[1];
    const float* eps      = (const float*)d_in[2];
    const float* qk_w     = (const float*)d_in[3];
    const float* we_p     = (const float*)d_in[4];
    const float* wr_p     = (const float*)d_in[5];
    const float* log_lam  = (const float*)d_in[6];
    const float* m_u      = (const float*)d_in[7];
    const float* s_tri    = (const float*)d_in[8];
    const float* log_ssqrt= (const float*)d_in[9];
    const float* fw_w     = (const float*)d_in[10];
    const float* fw_b     = (const float*)d_in[11];
    float* out = (float*)d_out;

    svgp_main<<<dim3(4096), 256, 0, stream>>>(x, mask, eps, qk_w, we_p, wr_p, log_lam,
                                              m_u, s_tri, log_ssqrt, fw_w, fw_b, out);
    svgp_kl<<<1, 256, 0, stream>>>(log_lam, m_u, s_tri, log_ssqrt, out);
}

// Round 3
// 456.899 us; speedup vs baseline: 8.8776x; 7.8363x over previous
//
#include <hip/hip_runtime.h>
#include <math.h>

#define Bv 8
#define Nv 2048
#define DIMv 1024
#define Hv 16
#define Dv 64
#define Rv 5
#define RMv 10

// output layout (flat concat, fp32)
#define ATTN_OFF 0
#define ESC_OFF (Bv * Nv * DIMv)              // 16777216
#define RSC_OFF (ESC_OFF + Bv * Hv * Nv * Rv) // 18087936
#define KL_OFF  (RSC_OFF + Bv * Hv * Nv * Rv) // 19398656

#define BMt 128      // rows per block
#define BK 64        // fp16 k-chunk
#define CT_STRIDE (128 + 4)

#define XHALFS (Bv * Nv * DIMv)     // 16777216
#define QKHALFS (2 * DIMv * DIMv)   // 2097152

using half8 = __attribute__((ext_vector_type(8))) _Float16;
using f32x4 = __attribute__((ext_vector_type(4))) float;

#define GLOAD(gp, lp)                                                      \
    __builtin_amdgcn_global_load_lds(                                      \
        (const __attribute__((address_space(1))) void*)(gp),               \
        (__attribute__((address_space(3))) void*)(lp), 16, 0, 0)

// ---- pre-pass: fp32 -> fp16 of x and qk_w into workspace
__global__ __launch_bounds__(256)
void convert_fp16(const float* __restrict__ x, const float* __restrict__ qk,
                  _Float16* __restrict__ xh, _Float16* __restrict__ qkh)
{
    size_t i = ((size_t)blockIdx.x * 256 + threadIdx.x) * 8;
    const float* src;
    _Float16* dst;
    if (i < XHALFS) { src = x + i; dst = xh + i; }
    else            { src = qk + (i - XHALFS); dst = qkh + (i - XHALFS); }
    float4 v0 = *(const float4*)src;
    float4 v1 = *(const float4*)(src + 4);
    half8 hv = {(_Float16)v0.x, (_Float16)v0.y, (_Float16)v0.z, (_Float16)v0.w,
                (_Float16)v1.x, (_Float16)v1.y, (_Float16)v1.z, (_Float16)v1.w};
    *(half8*)dst = hv;
}

// grid: 2048 1-D (xcd-affine: id&7 -> heads {2x,2x+1}); block: 256 = 4 waves
__global__ __launch_bounds__(256, 2)
void svgp_main(const _Float16* __restrict__ xh, const _Float16* __restrict__ qkh,
               const float* __restrict__ x, const float* __restrict__ mask,
               const float* __restrict__ eps,
               const float* __restrict__ we_p, const float* __restrict__ wr_p,
               const float* __restrict__ log_lam, const float* __restrict__ m_u,
               const float* __restrict__ s_tri, const float* __restrict__ log_ssqrt,
               const float* __restrict__ fw_w, const float* __restrict__ fw_b,
               float* __restrict__ out)
{
    const int id = blockIdx.x;
    const int h = 2 * (id & 7) + ((id >> 3) & 1);
    const int rowTile = id >> 4;           // 0..127
    const int row0 = rowTile * BMt;        // flat row base (b*N + n)
    const int b0 = row0 >> 11;             // batch (tile never straddles b)
    const int t = threadIdx.x;
    const int lane = t & 63;
    const int w = t >> 6;
    const int wu = __builtin_amdgcn_readfirstlane(w);   // wave-uniform

    // LDS: staging A(16KB)+B(16KB) aliased with C-tile fp32 128x132 (67.6KB)
    __shared__ float smem[BMt * CT_STRIDE];
    _Float16* sH = (_Float16*)smem;        // A slots [0,1024), B slots [1024,2048), 8 halfs each
    char* sBytes = (char*)smem;
    float (*sCt)[CT_STRIDE] = (float (*)[CT_STRIDE])smem;

    __shared__ float sS[Rv][Rv][Rv];
    __shared__ float sMu[Rv][Rv];
    __shared__ float sFw[Dv][Rv];
    __shared__ float sFb[Dv];
    __shared__ float sLam2[Rv];
    __shared__ float sWe[Dv][Rv];
    __shared__ float sWr[Dv][Rv];

    // ---- small tables (reads happen only after k-loop barriers)
    if (t < 125) {
        int a = t / 25, u = (t % 25) / 5, c = t % 5;
        float v = 0.f;
        if (u == c)      v = expf(log_ssqrt[(h * Rv + a) * Rv + u]);
        else if (u > c)  v = s_tri[((h * Rv + a) * Rv + u) * Rv + c];
        sS[a][u][c] = v;
    }
    if (t >= 128 && t < 153) { int i = t - 128; sMu[i / 5][i % 5] = m_u[h * Rv * Rv + i]; }
    if (t >= 160 && t < 165) sLam2[t - 160] = expf(2.f * log_lam[h * Rv + (t - 160)]);
    if (t >= 192 && t < 256) sFb[t - 192] = fw_b[t - 192];
    if (t < 320) sFw[t / Rv][t % Rv] = fw_w[t];
    { int t2 = t + 256; if (t2 < 320) sFw[t2 / Rv][t2 % Rv] = fw_w[t2]; }

    // ---- we/wr once per block (wave 0, lane = d), fp32
    if (t < 64) {
        float xv[RMv];
#pragma unroll
        for (int m = 0; m < RMv; ++m) {
            int nidx = (m == RMv - 1) ? (Nv - 1) : (int)((float)m * (2047.0f / 9.0f));
            xv[m] = x[((size_t)b0 * Nv + nidx) * DIMv + h * Dv + t];
        }
#pragma unroll
        for (int rr = 0; rr < Rv; ++rr) {
            float sw = 0.f, sr = 0.f;
#pragma unroll
            for (int m = 0; m < RMv; ++m) {
                sw = fmaf(xv[m], we_p[(h * RMv + m) * Rv + rr], sw);
                sr = fmaf(xv[m], wr_p[(h * RMv + m) * Rv + rr], sr);
            }
            sWe[t][rr] = sw; sWr[t][rr] = sr;
        }
    }

    // ---- staging address precompute (k0-invariant)
    // slot s = c*64 + lane; rl = (s>>7)*16 + (s&15); ko = (s>>4)&7
    // LDS lands fragment-major: slot = mtile*128 + ko*16 + mrow
    size_t aOff[4], bOff[4];
    int ldsOffA[4], ldsOffB[4];
#pragma unroll
    for (int j = 0; j < 4; ++j) {
        int c = wu * 4 + j;
        int s = c * 64 + lane;
        int rl = ((s >> 7) << 4) + (s & 15);
        int ko = (s >> 4) & 7;
        aOff[j] = (size_t)(row0 + rl) * DIMv + ko * 8;
        int grow = (rl < 64) ? (h * Dv + rl) : (DIMv + h * Dv + (rl - 64));
        bOff[j] = (size_t)grow * DIMv + ko * 8;
        ldsOffA[j] = c * 1024;             // bytes
        ldsOffB[j] = 16384 + c * 1024;
    }

    const int wm = wu >> 1, wn = wu & 1;
    f32x4 acc[4][4];
#pragma unroll
    for (int i = 0; i < 4; ++i)
#pragma unroll
        for (int j = 0; j < 4; ++j) acc[i][j] = (f32x4){0.f, 0.f, 0.f, 0.f};

    for (int k0 = 0; k0 < DIMv; k0 += BK) {
#pragma unroll
        for (int j = 0; j < 4; ++j) GLOAD(xh + aOff[j] + k0, sBytes + ldsOffA[j]);
#pragma unroll
        for (int j = 0; j < 4; ++j) GLOAD(qkh + bOff[j] + k0, sBytes + ldsOffB[j]);
        __syncthreads();

#pragma unroll
        for (int kk = 0; kk < 2; ++kk) {
            const int fo = (kk * 4 + (lane >> 4)) * 16 + (lane & 15);
            half8 af[4], bf[4];
#pragma unroll
            for (int i = 0; i < 4; ++i)
                af[i] = *(half8*)(sH + ((wm * 4 + i) * 128 + fo) * 8);
#pragma unroll
            for (int j = 0; j < 4; ++j)
                bf[j] = *(half8*)(sH + (1024 + (wn * 4 + j) * 128 + fo) * 8);
#pragma unroll
            for (int i = 0; i < 4; ++i)
#pragma unroll
                for (int j = 0; j < 4; ++j)
                    acc[i][j] = __builtin_amdgcn_mfma_f32_16x16x32_f16(af[i], bf[j], acc[i][j], 0, 0, 0);
        }
        __syncthreads();
    }

    // ---- spill C (col = lane&15 -> B dim, row = (lane>>4)*4+reg -> A dim)
#pragma unroll
    for (int i = 0; i < 4; ++i) {
        int rbase = wm * 64 + i * 16 + (lane >> 4) * 4;
        int col = wn * 64 + (lane & 15);
#pragma unroll
        for (int j = 0; j < 4; ++j)
#pragma unroll
            for (int reg = 0; reg < 4; ++reg)
                sCt[rbase + reg][col + j * 16] = acc[i][j][reg];
    }
    __syncthreads();

    // ---- epilogue: 4 rows/wave/pass; lane = rg*16 + dm, d-slice = dm*4..+4
    const int rg = lane >> 4;
    const int dm = lane & 15;
    const int d0 = dm * 4;

    float fwv[4][Rv], wev[4][Rv], wrv[4][Rv];
#pragma unroll
    for (int i = 0; i < 4; ++i)
#pragma unroll
        for (int rr = 0; rr < Rv; ++rr) {
            fwv[i][rr] = sFw[d0 + i][rr];
            wev[i][rr] = sWe[d0 + i][rr];
            wrv[i][rr] = sWr[d0 + i][rr];
        }
    float fbv[4];
#pragma unroll
    for (int i = 0; i < 4; ++i) fbv[i] = sFb[d0 + i];

    for (int p = 0; p < 8; ++p) {
        const int row = w * 32 + p * 4 + rg;
        const int nf = row0 + row;             // flat b*N+n
        const int n = nf & (Nv - 1);
        const float mk = mask[nf];

        float4 q4 = *(float4*)&sCt[row][d0];
        float4 k4 = *(float4*)&sCt[row][64 + d0];
        float qv[4] = {q4.x * mk, q4.y * mk, q4.z * mk, q4.w * mk};
        float kv[4] = {k4.x * mk, k4.y * mk, k4.z * mk, k4.w * mk};

        float red[12];
#pragma unroll
        for (int jj = 0; jj < 12; ++jj) red[jj] = 0.f;
#pragma unroll
        for (int i = 0; i < 4; ++i) {
            red[0] = fmaf(qv[i], qv[i], red[0]);
            red[1] = fmaf(kv[i], kv[i], red[1]);
#pragma unroll
            for (int rr = 0; rr < Rv; ++rr) {
                red[2 + rr] = fmaf(qv[i], wev[i][rr], red[2 + rr]);
                red[7 + rr] = fmaf(kv[i], wrv[i][rr], red[7 + rr]);
            }
        }
#pragma unroll
        for (int off = 8; off > 0; off >>= 1) {
#pragma unroll
            for (int jj = 0; jj < 12; ++jj)
                red[jj] += __shfl_xor(red[jj], off, 64);
        }
        const float qn = fmaxf(sqrtf(red[0]), 1e-12f);
        const float kn = fmaxf(sqrtf(red[1]), 1e-12f);

        float esc[Rv], rsc[Rv], v1[Rv];
#pragma unroll
        for (int rr = 0; rr < Rv; ++rr) {
            esc[rr] = red[2 + rr] / qn;
            rsc[rr] = red[7 + rr] / kn;
            v1[rr] = (esc[rr] + rsc[rr]) * sLam2[rr];
        }

        const size_t eb = (((size_t)(nf >> 11) * Hv + h) * Nv + n) * Rv;
        float ev[Rv];
#pragma unroll
        for (int u = 0; u < Rv; ++u) ev[u] = eps[eb + u];

        float smp[Rv];
#pragma unroll
        for (int c = 0; c < Rv; ++c) {
            float mn = 0.f;
#pragma unroll
            for (int a = 0; a < Rv; ++a) mn = fmaf(v1[a], sMu[a][c], mn);
            float nz = 0.f;
#pragma unroll
            for (int u = 0; u < Rv; ++u) {
                float s = 0.f;
#pragma unroll
                for (int a = 0; a < Rv; ++a) s = fmaf(v1[a], sS[a][u][c], s);
                nz = fmaf(s, ev[u], nz);
            }
            smp[c] = mn + nz;
        }

        float4 ao;
        float aov[4];
#pragma unroll
        for (int i = 0; i < 4; ++i) {
            float a = fbv[i];
#pragma unroll
            for (int rr = 0; rr < Rv; ++rr) a = fmaf(smp[rr], fwv[i][rr], a);
            aov[i] = a;
        }
        ao.x = aov[0]; ao.y = aov[1]; ao.z = aov[2]; ao.w = aov[3];
        *(float4*)&out[ATTN_OFF + (size_t)nf * DIMv + h * Dv + d0] = ao;

        if (dm == 0) {
#pragma unroll
            for (int rr = 0; rr < Rv; ++rr) {
                out[ESC_OFF + eb + rr] = esc[rr];
                out[RSC_OFF + eb + rr] = rsc[rr];
            }
        }
    }
}

__global__ void svgp_kl(const float* __restrict__ log_lam, const float* __restrict__ m_u,
                        const float* __restrict__ s_tri, const float* __restrict__ log_ssqrt,
                        float* __restrict__ out)
{
    __shared__ float red[256];
    const int t = threadIdx.x;
    float acc = 0.f;

    for (int idx = t; idx < Hv * Rv * Rv * Rv; idx += 256) {
        int hh = idx / 125;
        int rem = idx % 125;
        int a = rem / 25, u = (rem / 5) % 5, c = rem % 5;
        float S = 0.f;
        if (u == c)      S = expf(log_ssqrt[(hh * Rv + a) * Rv + u]);
        else if (u > c)  S = s_tri[((hh * Rv + a) * Rv + u) * Rv + c];
        float lam2 = expf(2.f * log_lam[hh * Rv + a]);
        float z = lam2 * S;
        acc += 0.5f * z * z;
    }
    for (int idx = t; idx < Hv * Rv * Rv; idx += 256) {
        int hh = idx / 25, a = (idx / 5) % 5;
        float e4 = expf(4.f * log_lam[hh * Rv + a]);
        float mu = m_u[idx];
        acc += 0.5f * e4 * mu * mu;
        acc -= log_ssqrt[idx];
    }
    for (int idx = t; idx < Hv * Rv; idx += 256) acc -= 2.f * (float)Rv * log_lam[idx];

    red[t] = acc;
    __syncthreads();
    for (int s = 128; s > 0; s >>= 1) {
        if (t < s) red[t] += red[t + s];
        __syncthreads();
    }
    if (t == 0) out[KL_OFF] = red[0] - 0.5f * (float)(Rv * Rv * Hv);
}

extern "C" void kernel_launch(void* const* d_in, const int* in_sizes, int n_in,
                              void* d_out, int out_size, void* d_ws, size_t ws_size,
                              hipStream_t stream) {
    const float* x        = (const float*)d_in[0];
    const float* mask     = (const float*)d_in[1];
    const float* eps      = (const float*)d_in[2];
    const float* qk_w     = (const float*)d_in[3];
    const float* we_p     = (const float*)d_in[4];
    const float* wr_p     = (const float*)d_in[5];
    const float* log_lam  = (const float*)d_in[6];
    const float* m_u      = (const float*)d_in[7];
    const float* s_tri    = (const float*)d_in[8];
    const float* log_ssqrt= (const float*)d_in[9];
    const float* fw_w     = (const float*)d_in[10];
    const float* fw_b     = (const float*)d_in[11];
    float* out = (float*)d_out;

    _Float16* xh  = (_Float16*)d_ws;
    _Float16* qkh = xh + XHALFS;

    convert_fp16<<<dim3((XHALFS + QKHALFS) / 8 / 256), 256, 0, stream>>>(x, qk_w, xh, qkh);
    svgp_main<<<dim3(2048), 256, 0, stream>>>(xh, qkh, x, mask, eps, we_p, wr_p,
                                              log_lam, m_u, s_tri, log_ssqrt, fw_w, fw_b, out);
    svgp_kl<<<1, 256, 0, stream>>>(log_lam, m_u, s_tri, log_ssqrt, out);
}